// Round 8
// baseline (357.961 us; speedup 1.0000x reference)
//
#include <hip/hip_runtime.h>
#include <math.h>
#include <stdint.h>

#define NTOK  16384
#define NW6   (NTOK * 6)
#define D4    512              // float4 per full 2048-dim row
#define WHF4  1152             // 18 rows x 64 float4 per HALF-segment (18,432 B)
#define XTF4  512              // per-wave tile: 8 tokens x 64 float4 (8 KB)
// smem float4 count: W half-seg + 8 waves x 2-tile ring = 1152 + 8192 = 9344
// -> 149,504 B (+ lcnt) <= 160 KiB -> 1 block (8 waves) per CU.

#define DOT4(a, b) ((a).x*(b).x + (a).y*(b).y + (a).z*(b).z + (a).w*(b).w)

// Async global->LDS DMA, 16 B per lane. LDS dest = wave-uniform base +
// lane*16 (contiguous); global src is per-lane. No destination VGPRs.
#define ASYNC_CP16(gsrc, ldst)                                              \
    __builtin_amdgcn_global_load_lds(                                       \
        (const __attribute__((address_space(1))) void*)(gsrc),              \
        (__attribute__((address_space(3))) void*)(ldst), 16, 0, 0)

// Counted vmem wait. "memory" clobber: compiler cannot move LDS reads or
// DMA issues across it.
template <int N>
__device__ __forceinline__ void waitv() {
    asm volatile("s_waitcnt vmcnt(%0)" :: "i"(N) : "memory");
}

// DPP row_shl sum-tree: lane i adds lane i+N (out-of-range -> 0). After 4
// steps lane 0 of each 16-lane row holds the full row sum. (Verified.)
template <int CTRL>
__device__ __forceinline__ float dpp_add(float v) {
    int moved = __builtin_amdgcn_update_dpp(0, __float_as_int(v),
                                            CTRL, 0xF, 0xF, true);
    return v + __int_as_float(moved);
}
__device__ __forceinline__ float row_reduce16(float v) {
    v = dpp_add<0x108>(v);   // row_shl:8
    v = dpp_add<0x104>(v);   // row_shl:4
    v = dpp_add<0x102>(v);   // row_shl:2
    v = dpp_add<0x101>(v);   // row_shl:1
    return v;
}

// Routing math for one token given its 18 full scores (math identical to
// reference `_router`; harness-verified in rounds 1, 5, 6, 7).
__device__ __forceinline__ void route_one(const float* __restrict__ s,
                                          int tok,
                                          float* __restrict__ out,
                                          unsigned int* __restrict__ lcnt)
{
    const float g0 = 1.f / (1.f + expf(-s[16]));
    const float g1 = 1.f / (1.f + expf(-s[17]));

    // --- Group A: experts 0..7, top-1 of softmax ---
    int aidx = 0; float amax = s[0];
#pragma unroll
    for (int i = 1; i < 8; ++i)
        if (s[i] > amax) { amax = s[i]; aidx = i; }
    float asum = 0.f;
#pragma unroll
    for (int i = 0; i < 8; ++i) asum += expf(s[i] - amax);
    const float a_best = 1.f / asum;

    // --- Group B: experts 8..11, top-1, gated by g0 ---
    int bidx = 0; float bmax = s[8];
#pragma unroll
    for (int i = 1; i < 4; ++i)
        if (s[8 + i] > bmax) { bmax = s[8 + i]; bidx = i; }
    float bsum = 0.f;
#pragma unroll
    for (int i = 0; i < 4; ++i) bsum += expf(s[8 + i] - bmax);
    const float b_w = (g0 > 0.15f) ? ((1.f / bsum) * g0) : 0.f;

    // --- Group C: experts 12..15, top-2 of softmax, gated by g1 ---
    int c1 = 0; float cmax = s[12];
#pragma unroll
    for (int i = 1; i < 4; ++i)
        if (s[12 + i] > cmax) { cmax = s[12 + i]; c1 = i; }
    float csum = 0.f;
#pragma unroll
    for (int i = 0; i < 4; ++i) csum += expf(s[12 + i] - cmax);
    int c2 = -1; float c2v = -1e30f;
#pragma unroll
    for (int i = 0; i < 4; ++i)
        if (i != c1 && s[12 + i] > c2v) { c2v = s[12 + i]; c2 = i; }
    const float cg   = (g1 > 0.15f) ? g1 : 0.f;
    const float c_w1 = (1.f / csum) * cg;
    const float c_w2 = (expf(c2v - cmax) / csum) * cg;

    // --- normalize and write ---
    const float inv = 1.f / (a_best + b_w + c_w1 + c_w2 + 1e-8f);
    float2* ow = reinterpret_cast<float2*>(out + (size_t)tok * 6);
    ow[0] = make_float2(a_best * inv, b_w * inv);
    ow[1] = make_float2(c_w1 * inv, c_w2 * inv);
    ow[2] = make_float2(0.f, 0.f);
    float2* oi = reinterpret_cast<float2*>(out + NW6 + (size_t)tok * 6);
    oi[0] = make_float2((float)aidx, (float)(8 + bidx));
    oi[1] = make_float2((float)(12 + c1), (float)(12 + c2));
    oi[2] = make_float2(0.f, 0.f);

    atomicAdd(&lcnt[aidx], 1u);
    atomicAdd(&lcnt[8 + bidx], 1u);
    atomicAdd(&lcnt[12 + c1], 1u);
    atomicAdd(&lcnt[12 + c2], 1u);
}

// ---------------- Fused: scores over full D + routing + aux ----------------
// 256 blocks x 64 tokens x 8 waves. DRAM-page-friendly: every x DMA
// instruction reads 1 KB CONTIGUOUS from one token row (lane*16B), and each
// row is swept in 8 sequential 1 KB touches (tiles of 256 dims). Per-wave
// 2-tile ring; tile hs+1 issued during compute of tile hs; the only waits
// are the 7 half-segment W-restage boundaries.
//
// OCCUPANCY/RA NOTE (rounds 6-7 post-mortem): 150 KB LDS -> exactly 1 block
// (2 waves/EU) can be resident. But LLVM's register allocator targets its
// DEFAULT 4 waves/EU unless the MAXIMUM is capped -- __launch_bounds__'s 2nd
// arg only sets the minimum and left the cap at 128 VGPRs, spilling the
// accumulators (283 MB phantom WRITE_SIZE, 2.4x slowdown). waves_per_eu(1,2)
// caps the target at the occupancy LDS permits anyway -> 256-VGPR budget,
// no spill.
__global__
__attribute__((amdgpu_flat_work_group_size(512, 512)))
__attribute__((amdgpu_waves_per_eu(1, 2)))
void fused_router_kernel(
    const float* __restrict__ x,
    const float* __restrict__ We,
    const float* __restrict__ Wg,
    float* __restrict__ out,
    unsigned int* __restrict__ gcounts)
{
    __shared__ float4 smem[WHF4 + 8 * 2 * XTF4];   // 149,504 B
    __shared__ unsigned int lcnt[16];

    const int tid   = threadIdx.x;
    const int strip = blockIdx.x;           // 0..255, 64 tokens each

    const float4* __restrict__ x4  = reinterpret_cast<const float4*>(x);
    const float4* __restrict__ We4 = reinterpret_cast<const float4*>(We);
    const float4* __restrict__ Wg4 = reinterpret_cast<const float4*>(Wg);

    const int wave  = tid >> 6;             // 0..7
    const int lane  = tid & 63;
    const int l16   = lane & 15;
    const int gl    = lane >> 4;            // 16-lane group within wave, 0..3
    const int xbase = WHF4 + wave * (2 * XTF4);   // this wave's tile ring

    // Stage W half-segment hs (18 experts x 256 dims = 18 KB). Each DMA
    // instruction reads 1 KB contiguous from ONE W row (also page-friendly).
    auto stage_W = [&](int hs) {
        for (int e = wave; e < 18; e += 8) {
            const float4* gsrc = ((e < 16) ? (We4 + (size_t)e * D4)
                                           : (Wg4 + (size_t)(e - 16) * D4))
                                 + hs * 64 + lane;
            ASYNC_CP16(gsrc, smem + e * 64);
        }
    };

    // Issue tile tt (256 dims x this wave's 8 tokens) into ring slot tt&1.
    // 8 instructions, each 1 KB contiguous from one token row.
    auto issue_tile = [&](int tt) {
        const int buf = tt & 1;
#pragma unroll
        for (int t = 0; t < 8; ++t) {
            const float4* gsrc = x4 + (size_t)(strip * 64 + wave * 8 + t) * D4
                                 + tt * 64 + lane;
            ASYNC_CP16(gsrc, smem + xbase + buf * XTF4 + t * 64);
        }
    };

    float a0[18], a1[18];
#pragma unroll
    for (int e = 0; e < 18; ++e) { a0[e] = 0.f; a1[e] = 0.f; }

    // Compute one 64-dim chunk (ch2 within tile hs). Group gl handles
    // tokens 2gl, 2gl+1 of this wave; l16 spans the 64 dims.
    auto compute = [&](int hs, int ch2) {
        const int buf = hs & 1;
        const float4* xc = smem + xbase + buf * XTF4
                           + (gl * 2) * 64 + ch2 * 16 + l16;
        const float4 xv0 = xc[0];       // token 2gl
        const float4 xv1 = xc[64];      // token 2gl+1
#pragma unroll
        for (int e = 0; e < 18; ++e) {
            const float4 w = smem[e * 64 + ch2 * 16 + l16];  // broadcast
            a0[e] += DOT4(w, xv0);
            a1[e] += DOT4(w, xv1);
        }
    };

    // ---- prologue: W half-seg 0 + tile 0; full drain ----
    stage_W(0);
    issue_tile(0);
    if (tid < 16) lcnt[tid] = 0u;
    __syncthreads();                    // vmcnt(0) drain: W0 + tile0 resident

    for (int hs = 0; hs < 8; ++hs) {
        if (hs) {
            // All waves consumed old-W reads (every ds_read feeds an FMA
            // before this point) -> safe to overwrite after barrier.
            __builtin_amdgcn_s_barrier();
            stage_W(hs);
            waitv<0>();                 // own W loads + tile-hs prefetch landed
            __builtin_amdgcn_s_barrier();  // everyone's W slice resident
        }
        if (hs < 7) issue_tile(hs + 1); // overlaps this tile's compute
#pragma unroll
        for (int ch2 = 0; ch2 < 4; ++ch2) compute(hs, ch2);
    }

    // ---- reduce 36 sums across each 16-lane group (pure VALU) ----
#pragma unroll
    for (int e = 0; e < 18; ++e) {
        a0[e] = row_reduce16(a0[e]);
        a1[e] = row_reduce16(a1[e]);
    }

    // ---- routing: lane 0 of each group handles its 2 tokens ----
    if (l16 == 0) {
        const int tok = strip * 64 + wave * 8 + gl * 2;
        route_one(a0, tok,     out, lcnt);
        route_one(a1, tok + 1, out, lcnt);
    }

    __syncthreads();
    if (tid < 16) {
        const unsigned int c = lcnt[tid];
        if (c) atomicAdd(&gcounts[tid], c);
    }
    __syncthreads();

    // Last-block ticket: aux loss. Reference bincount counts the 2 zero-pad
    // indices per token -> expert 0 gets +2*NTOK; total = 6*NTOK.
    if (tid == 0) {
        __threadfence();
        const unsigned int t = atomicAdd(&gcounts[16], 1u);
        if (t == gridDim.x - 1) {
            const float total = 6.0f * (float)NTOK;
            const float uni = 1.0f / 16.0f;
            float aux = 0.f;
            for (int e = 0; e < 16; ++e) {
                float c = (float)atomicAdd(&gcounts[e], 0u)
                          + (e == 0 ? 2.0f * (float)NTOK : 0.0f);
                aux += uni * (logf(uni) - logf(c / total));
            }
            out[2 * NW6] = aux * 0.01f;
        }
    }
}

extern "C" void kernel_launch(void* const* d_in, const int* in_sizes, int n_in,
                              void* d_out, int out_size, void* d_ws, size_t ws_size,
                              hipStream_t stream)
{
    const float* x  = (const float*)d_in[0];   // (4,4096,2048)
    const float* We = (const float*)d_in[1];   // (16,2048)
    const float* Wg = (const float*)d_in[2];   // (2,2048)
    float* out = (float*)d_out;

    unsigned int* counts = (unsigned int*)d_ws;

    hipMemsetAsync(counts, 0, 17 * sizeof(unsigned int), stream);

    // Single fused kernel: 256 strips of 64 tokens, 8 waves each.
    fused_router_kernel<<<dim3(256), 512, 0, stream>>>(x, We, Wg, out, counts);
}

// Round 9
// 227.427 us; speedup vs baseline: 1.5740x; 1.5740x over previous
//
#include <hip/hip_runtime.h>
#include <math.h>
#include <stdint.h>

#define NTOK  16384
#define NW6   (NTOK * 6)
#define D4    512              // float4 per full 2048-dim row
#define WF4   2304             // 18 rows x 128 float4 per D-segment (36,864 B)
#define XWAVE 512              // 4 bufs x 128 float4 per wave (8 KB/wave)
#define NCC   32               // 64-dim chunks across full D (4 seg x 8)

#define DOT4(a, b) ((a).x*(b).x + (a).y*(b).y + (a).z*(b).z + (a).w*(b).w)

// Async global->LDS DMA, 16 B per lane. LDS dest = wave-uniform base +
// lane*16 (contiguous); global src is per-lane. No destination VGPRs.
#define ASYNC_CP16(gsrc, ldst)                                              \
    __builtin_amdgcn_global_load_lds(                                       \
        (const __attribute__((address_space(1))) void*)(gsrc),              \
        (__attribute__((address_space(3))) void*)(ldst), 16, 0, 0)

// Counted vmem wait (T4): never drain to 0 in the main loop. "memory"
// clobber stops the compiler hoisting the dependent ds_reads above it.
template <int N>
__device__ __forceinline__ void waitv() {
    asm volatile("s_waitcnt vmcnt(%0)" :: "i"(N) : "memory");
}

// DPP row_shl sum-tree: lane i adds lane i+N (out-of-range -> 0). After 4
// steps lane 0 of each 16-lane row holds the full row sum. (Verified.)
template <int CTRL>
__device__ __forceinline__ float dpp_add(float v) {
    int moved = __builtin_amdgcn_update_dpp(0, __float_as_int(v),
                                            CTRL, 0xF, 0xF, true);
    return v + __int_as_float(moved);
}
__device__ __forceinline__ float row_reduce16(float v) {
    v = dpp_add<0x108>(v);   // row_shl:8
    v = dpp_add<0x104>(v);   // row_shl:4
    v = dpp_add<0x102>(v);   // row_shl:2
    v = dpp_add<0x101>(v);   // row_shl:1
    return v;
}

// Routing math for one token given its 18 full scores (math identical to
// reference `_router`; harness-verified rounds 1, 5-8).
__device__ __forceinline__ void route_one(const float* __restrict__ s,
                                          int tok,
                                          float* __restrict__ out,
                                          unsigned int* __restrict__ lcnt)
{
    const float g0 = 1.f / (1.f + expf(-s[16]));
    const float g1 = 1.f / (1.f + expf(-s[17]));

    // --- Group A: experts 0..7, top-1 of softmax ---
    int aidx = 0; float amax = s[0];
#pragma unroll
    for (int i = 1; i < 8; ++i)
        if (s[i] > amax) { amax = s[i]; aidx = i; }
    float asum = 0.f;
#pragma unroll
    for (int i = 0; i < 8; ++i) asum += expf(s[i] - amax);
    const float a_best = 1.f / asum;

    // --- Group B: experts 8..11, top-1, gated by g0 ---
    int bidx = 0; float bmax = s[8];
#pragma unroll
    for (int i = 1; i < 4; ++i)
        if (s[8 + i] > bmax) { bmax = s[8 + i]; bidx = i; }
    float bsum = 0.f;
#pragma unroll
    for (int i = 0; i < 4; ++i) bsum += expf(s[8 + i] - bmax);
    const float b_w = (g0 > 0.15f) ? ((1.f / bsum) * g0) : 0.f;

    // --- Group C: experts 12..15, top-2 of softmax, gated by g1 ---
    int c1 = 0; float cmax = s[12];
#pragma unroll
    for (int i = 1; i < 4; ++i)
        if (s[12 + i] > cmax) { cmax = s[12 + i]; c1 = i; }
    float csum = 0.f;
#pragma unroll
    for (int i = 0; i < 4; ++i) csum += expf(s[12 + i] - cmax);
    int c2 = -1; float c2v = -1e30f;
#pragma unroll
    for (int i = 0; i < 4; ++i)
        if (i != c1 && s[12 + i] > c2v) { c2v = s[12 + i]; c2 = i; }
    const float cg   = (g1 > 0.15f) ? g1 : 0.f;
    const float c_w1 = (1.f / csum) * cg;
    const float c_w2 = (expf(c2v - cmax) / csum) * cg;

    // --- normalize and write ---
    const float inv = 1.f / (a_best + b_w + c_w1 + c_w2 + 1e-8f);
    float2* ow = reinterpret_cast<float2*>(out + (size_t)tok * 6);
    ow[0] = make_float2(a_best * inv, b_w * inv);
    ow[1] = make_float2(c_w1 * inv, c_w2 * inv);
    ow[2] = make_float2(0.f, 0.f);
    float2* oi = reinterpret_cast<float2*>(out + NW6 + (size_t)tok * 6);
    oi[0] = make_float2((float)aidx, (float)(8 + bidx));
    oi[1] = make_float2((float)(12 + c1), (float)(12 + c2));
    oi[2] = make_float2(0.f, 0.f);

    atomicAdd(&lcnt[aidx], 1u);
    atomicAdd(&lcnt[8 + bidx], 1u);
    atomicAdd(&lcnt[12 + c1], 1u);
    atomicAdd(&lcnt[12 + c2], 1u);
}

// ---------------- Fused: scores over full D + routing + aux ----------------
// EXACT round-5 structure (harness-verified clean: VGPR 100, no scratch,
// 93 us) + ONE change: each block walks the 4 D-segments in a ROTATED order
// (boff = strip & 3). All 16K token streams previously walked D in the same
// order -> at any instant the chip issued addresses at stride 8 KB with a
// common offset, aliasing to a small subset of HBM channel groups. Rotation
// spreads concurrent offsets 2 KB apart (accumulation is order-independent;
// addresses only -- ring slots and vmcnt stay iteration-indexed).
// LDS: 36,864 (W) + 4 waves x 8,192 (x rings) = 69,696 B -> 2 blocks/CU.
__global__ __launch_bounds__(256, 2) void fused_router_kernel(
    const float* __restrict__ x,
    const float* __restrict__ We,
    const float* __restrict__ Wg,
    float* __restrict__ out,
    unsigned int* __restrict__ gcounts)
{
    __shared__ float4 smem[WF4 + 4 * XWAVE];   // 36,864 + 32,768 B
    __shared__ unsigned int lcnt[16];

    const int tid   = threadIdx.x;
    const int strip = blockIdx.x;           // 0..511, 32 tokens each
    const int boff  = strip & 3;            // D-segment rotation offset

    const float4* __restrict__ x4  = reinterpret_cast<const float4*>(x);
    const float4* __restrict__ We4 = reinterpret_cast<const float4*>(We);
    const float4* __restrict__ Wg4 = reinterpret_cast<const float4*>(Wg);

    const int wave  = tid >> 6;
    const int lane  = tid & 63;
    const int l16   = lane & 15;
    const int gl    = lane >> 4;            // 16-lane group within wave, 0..3
    const int xbase = WF4 + wave * XWAVE;   // this wave's x ring (float4 idx)

    // Stage the 18x512-dim W segment `seg` into LDS (9 DMA instr/wave).
    auto stage_W = [&](int seg) {
#pragma unroll
        for (int k = 0; k < 9; ++k) {
            const int idx = wave * 576 + k * 64 + lane;    // 0..2303
            const int e = idx >> 7;                        // 0..17
            const int d = idx & 127;
            const float4* gsrc = ((e < 16) ? (We4 + (size_t)e * D4)
                                           : (Wg4 + (size_t)(e - 16) * D4))
                                 + seg * 128 + d;
            ASYNC_CP16(gsrc, smem + wave * 576 + k * 64);
        }
    };

    // Rotated chunk address for iteration k: segment ((k>>3)+boff)&3,
    // within-segment chunk k&7.
    auto ccof = [&](int k) {
        return ((((k >> 3) + boff) & 3) << 3) + (k & 7);
    };

    // Issue this wave's 8 tokens x 64 dims of iteration k into ring slot
    // k&3 (2 DMA instr). Token t lands at float4 offset t*16 in the slot.
    auto issue_x = [&](int k) {
        const int buf = k & 3;
        const int cc  = ccof(k);
#pragma unroll
        for (int i = 0; i < 2; ++i) {
            const int t = wave * 8 + i * 4 + (lane >> 4);
            const float4* gsrc = x4 + (size_t)(strip * 32 + t) * D4
                                 + cc * 16 + l16;
            ASYNC_CP16(gsrc, smem + xbase + buf * 128 + i * 64);
        }
    };

    float a0[18], a1[18];
#pragma unroll
    for (int e = 0; e < 18; ++e) { a0[e] = 0.f; a1[e] = 0.f; }

    // Compute iteration k from ring slot k&3 against W column k&7 of the
    // currently-staged segment (within-segment layout is seg-independent).
    auto compute = [&](int k) {
        const int ch  = k & 7;
        const int buf = k & 3;
        const float4* xcur = smem + xbase + buf * 128 + gl * 32 + l16;
        const float4 xv0 = xcur[0];     // token 2gl
        const float4 xv1 = xcur[16];    // token 2gl+1
#pragma unroll
        for (int e = 0; e < 18; ++e) {
            const float4 w = smem[e * 128 + ch * 16 + l16];  // broadcast
            a0[e] += DOT4(w, xv0);
            a1[e] += DOT4(w, xv1);
        }
    };

    // ---- prologue: W segment boff + iterations 0..2; full drain ----
    stage_W(boff);
    issue_x(0); issue_x(1); issue_x(2);
    if (tid < 16) lcnt[tid] = 0u;
    __syncthreads();                    // vmcnt(0) drain: W + k=0..2 resident

    for (int s = 0; s < 4; ++s) {
        if (s) {
            // All waves done READING old W (every ds_read consumed before
            // this point) -> safe to overwrite after barrier.
            __builtin_amdgcn_s_barrier();
            stage_W((s + boff) & 3);
            waitv<0>();                 // own W loads + x prefetches landed
            __builtin_amdgcn_s_barrier();  // everyone's W slice resident
        }
        const int lim = (s == 3) ? 5 : 8;
        for (int i = 0; i < lim; ++i) {
            const int k = s * 8 + i;        // k <= 28 here
            issue_x(k + 3);                 // 3 iters ahead, 6 loads in flight
            waitv<6>();                     // iteration k resident
            compute(k);
        }
    }
    // ---- tail: drain the last 3 iterations with counted waits ----
    waitv<4>(); compute(29);
    waitv<2>(); compute(30);
    waitv<0>(); compute(31);

    // ---- reduce 36 sums across each 16-lane group (pure VALU) ----
#pragma unroll
    for (int e = 0; e < 18; ++e) {
        a0[e] = row_reduce16(a0[e]);
        a1[e] = row_reduce16(a1[e]);
    }

    // ---- routing: lane 0 of each group handles its 2 tokens ----
    const int g = tid >> 4;             // block-level group id, 0..15
    if (l16 == 0) {
        const int tok = strip * 32 + g * 2;
        route_one(a0, tok,     out, lcnt);
        route_one(a1, tok + 1, out, lcnt);
    }

    __syncthreads();
    if (tid < 16) {
        const unsigned int c = lcnt[tid];
        if (c) atomicAdd(&gcounts[tid], c);
    }
    __syncthreads();

    // Last-block ticket: aux loss. Reference bincount counts the 2 zero-pad
    // indices per token -> expert 0 gets +2*NTOK; total = 6*NTOK.
    if (tid == 0) {
        __threadfence();
        const unsigned int t = atomicAdd(&gcounts[16], 1u);
        if (t == gridDim.x - 1) {
            const float total = 6.0f * (float)NTOK;
            const float uni = 1.0f / 16.0f;
            float aux = 0.f;
            for (int e = 0; e < 16; ++e) {
                float c = (float)atomicAdd(&gcounts[e], 0u)
                          + (e == 0 ? 2.0f * (float)NTOK : 0.0f);
                aux += uni * (logf(uni) - logf(c / total));
            }
            out[2 * NW6] = aux * 0.01f;
        }
    }
}

extern "C" void kernel_launch(void* const* d_in, const int* in_sizes, int n_in,
                              void* d_out, int out_size, void* d_ws, size_t ws_size,
                              hipStream_t stream)
{
    const float* x  = (const float*)d_in[0];   // (4,4096,2048)
    const float* We = (const float*)d_in[1];   // (16,2048)
    const float* Wg = (const float*)d_in[2];   // (2,2048)
    float* out = (float*)d_out;

    unsigned int* counts = (unsigned int*)d_ws;

    hipMemsetAsync(counts, 0, 17 * sizeof(unsigned int), stream);

    // Single fused kernel: 512 token-strips of 32 tokens, 4 waves each.
    fused_router_kernel<<<dim3(512), 256, 0, stream>>>(x, We, Wg, out, counts);
}